// Round 10
// baseline (96.258 us; speedup 1.0000x reference)
//
#include <hip/hip_runtime.h>
#include <hip/hip_bf16.h>
#include <stdint.h>

// Problem constants: A=2048 agents, H=128, G=8 (64 cells), NB=32, CELL=8
// pooled = (grid[A,64,128] flattened) @ W.T + b ; out masked by valid_i.

typedef __attribute__((ext_vector_type(4))) float f32x4;
typedef __attribute__((ext_vector_type(8))) short short8;

// workspace layout (bytes)
#define O_HB   0u          // bf16 hidden [2049][128]  (row 2048 = zeros, dummy target)
#define O_WB   1048576u    // bf16 W      [128][8192]
#define O_GRID 3145728u    // bf16 grid   [2048][8192]
#define O_PART 36700160u   // f32 partials [16][2048][128] (written by gemm)
// Overlay of O_PART (consumed by sp_gath2 BEFORE sp_gemm writes part):
#define O_LIST 36700160u   // u16 lists [2048][2240] cell-sorted j (x4-padded, dummy=2048)
#define O_OFFS 46137344u   // int offs  [2048][65] padded exclusive offsets
#define O_POSM 46669824u   // float2 posm[2048] NaN-poisoned positions
// total ~51 MB

__device__ __forceinline__ void gl_lds16(const void* g, void* l) {
  __builtin_amdgcn_global_load_lds((const __attribute__((address_space(1))) void*)g,
                                   (__attribute__((address_space(3))) void*)l, 16, 0, 0);
}

__device__ __forceinline__ float bf_lo(uint32_t w) {
  union { uint32_t u; float f; } v{w << 16}; return v.f;
}
__device__ __forceinline__ float bf_hi(uint32_t w) {
  union { uint32_t u; float f; } v{w & 0xffff0000u}; return v.f;
}
__device__ __forceinline__ uint32_t pack_bf2(float x, float y) {
  __hip_bfloat16 bx = __float2bfloat16(x), by = __float2bfloat16(y);
  return ((uint32_t)(*(unsigned short*)&by) << 16) | (*(unsigned short*)&bx);
}

// ---------------- prep: f32 -> bf16 conversions + NaN-poisoned posm ----------------
__global__ __launch_bounds__(256) void sp_prep(const float* __restrict__ hidden,
                                               const float* __restrict__ W,
                                               const float* __restrict__ pos,
                                               const int* __restrict__ mask,
                                               __hip_bfloat16* __restrict__ hb,
                                               __hip_bfloat16* __restrict__ wb,
                                               float2* __restrict__ posm) {
  int idx = blockIdx.x * 256 + threadIdx.x;
  const int HID4 = (2049 * 128) / 4;   // 65568 groups of 4
  const int W4   = (128 * 8192) / 4;   // 262144 groups of 4
  if (idx < HID4) {
    int e = idx * 4;
    float4 v = make_float4(0.f, 0.f, 0.f, 0.f);
    if (e < 2048 * 128) v = *reinterpret_cast<const float4*>(hidden + e);
    ushort4 pk;
    pk.x = (ushort)(pack_bf2(v.x, v.x) & 0xffffu);
    pk.y = (ushort)(pack_bf2(v.y, v.y) & 0xffffu);
    pk.z = (ushort)(pack_bf2(v.z, v.z) & 0xffffu);
    pk.w = (ushort)(pack_bf2(v.w, v.w) & 0xffffu);
    *reinterpret_cast<ushort4*>(hb + e) = pk;
  } else if (idx < HID4 + W4) {
    int e = (idx - HID4) * 4;
    float4 v = *reinterpret_cast<const float4*>(W + e);
    ushort4 pk;
    pk.x = (ushort)(pack_bf2(v.x, v.x) & 0xffffu);
    pk.y = (ushort)(pack_bf2(v.y, v.y) & 0xffffu);
    pk.z = (ushort)(pack_bf2(v.z, v.z) & 0xffffu);
    pk.w = (ushort)(pack_bf2(v.w, v.w) & 0xffffu);
    *reinterpret_cast<ushort4*>(wb + e) = pk;
  } else {
    int j = idx - (HID4 + W4);
    if (j < 2048) {
      float2 p = reinterpret_cast<const float2*>(pos)[j];
      union { uint32_t u; float f; } qn{0x7fc00000u};  // quiet NaN
      float2 o;
      bool m = (mask[j] != 0);
      o.x = m ? p.x : qn.f;
      o.y = m ? p.y : qn.f;
      posm[j] = o;
    }
  }
}

// ---------------- bins: wave-per-agent counting sort -> GLOBAL u16 lists (R3 format) --
// 512 blocks x 256 (4 waves), one agent per wave, wave-private. Emits exactly the
// list/offs format R3's phase D consumed: u16 j values, cells padded to x4 with
// dummy 2048 (zero row of hb), padded exclusive offsets offs[65].
__global__ __launch_bounds__(256) void sp_bins(const float* __restrict__ pos,
                                               const float2* __restrict__ posm,
                                               uint16_t* __restrict__ listG,
                                               int* __restrict__ offsG) {
  __shared__ int hist[4][64];
  __shared__ int curs[4][64];
  int t = threadIdx.x;
  int wv = t >> 6;
  int lane = t & 63;
  int i = blockIdx.x * 4 + wv;           // this wave's agent
  float pxi = pos[2 * i], pyi = pos[2 * i + 1];
  hist[wv][lane] = 0;
  // Phase A: bin all 2048 j's; pack 32 bins into 8 regs (byte each, static idx)
  uint32_t bp[8];
  #pragma unroll
  for (int r = 0; r < 8; ++r) bp[r] = 0;
  #pragma unroll
  for (int ch = 0; ch < 32; ++ch) {
    int j = ch * 64 + lane;
    float2 pj = posm[j];
    float rx = pj.x - pxi, ry = pj.y - pyi;
    // NaN rel (masked-out j or NaN pos) -> comparisons false -> invalid
    bool ok = (fabsf(rx) < 32.f) && (fabsf(ry) < 32.f) && (j != i);
    uint32_t b = 255;
    if (ok) {
      // rx,ry in (-32,32): (rx+32)*0.125 in [0,8) exactly; clip is a no-op
      int col = (int)floorf((rx + 32.f) * 0.125f);
      int row = (int)floorf((ry + 32.f) * 0.125f);
      b = (uint32_t)(row * 8 + col);
      atomicAdd(&hist[wv][b], 1);        // int LDS atomic (native)
    }
    bp[ch >> 2] |= b << ((ch & 3) * 8);
  }
  // Phase B: wave shfl prefix scan over x4-padded cell counts (lane = cell)
  int h = hist[wv][lane];
  int pc = (h + 3) & ~3;
  int x = pc;
  #pragma unroll
  for (int d = 1; d < 64; d <<= 1) {
    int y = __shfl_up(x, d);
    if (lane >= d) x += y;
  }
  int start = x - pc;
  curs[wv][lane] = start;
  offsG[i * 65 + lane] = start;
  if (lane == 63) offsG[i * 65 + 64] = x;   // total (padded)
  // Phase C: scatter u16 j (intra-wave int atomics only)
  uint16_t* lrow = listG + (size_t)i * 2240;
  #pragma unroll
  for (int ch = 0; ch < 32; ++ch) {
    uint32_t b = (bp[ch >> 2] >> ((ch & 3) * 8)) & 255u;
    if (b != 255u) {
      int slot = atomicAdd(&curs[wv][b], 1);
      lrow[slot] = (uint16_t)(ch * 64 + lane);
    }
  }
  // Phase Pad: lane = cell writes its own pad slots [start+h, start+pc) (disjoint)
  for (int p = h; p < pc; ++p) lrow[start + p] = 2048;
}

// ---------------- gath2: R3's winning phase-D loop, fed from global lists ----------
// 2048 blocks x 256 (one agent per block). Copy list+offs global->LDS (coalesced),
// then run R3's phase D VERBATIM: thread = column h (128), par in {0,1} takes
// even/odd cells, 4 accumulation streams over 4-row quads, scalar 2B gathers.
__global__ __launch_bounds__(256) void sp_gath2(const uint16_t* __restrict__ listG,
                                                const int* __restrict__ offsG,
                                                const __hip_bfloat16* __restrict__ hb,
                                                __hip_bfloat16* __restrict__ grid) {
  __shared__ __align__(8) uint16_t list[2304];
  __shared__ int offs[65];
  int t = threadIdx.x;
  int i = blockIdx.x;
  // copy offs + full list row into LDS (coalesced u32 reads)
  if (t < 65) offs[t] = offsG[i * 65 + t];
  {
    const uint32_t* lg = reinterpret_cast<const uint32_t*>(listG + (size_t)i * 2240);
    uint32_t* ll = reinterpret_cast<uint32_t*>(list);
    #pragma unroll
    for (int q = 0; q < 5; ++q) {
      int k = t + q * 256;
      if (k < 1120) ll[k] = lg[k];
    }
  }
  __syncthreads();
  // R3 phase D (verbatim): thread = h, par takes even/odd cells
  int h = t & 127;
  int par = t >> 7;
  const __hip_bfloat16* hbh = hb + h;
  for (int c = par; c < 64; c += 2) {
    int s0 = offs[c], e0 = offs[c + 1];
    float a0 = 0.f, a1 = 0.f, a2 = 0.f, a3 = 0.f;
    for (int k = s0; k < e0; k += 4) {
      unsigned long long q = *reinterpret_cast<const unsigned long long*>(&list[k]);
      int j0 = (int)(q & 0xffffu);
      int j1 = (int)((q >> 16) & 0xffffu);
      int j2 = (int)((q >> 32) & 0xffffu);
      int j3 = (int)((q >> 48) & 0xffffu);
      a0 += __bfloat162float(hbh[j0 << 7]);
      a1 += __bfloat162float(hbh[j1 << 7]);
      a2 += __bfloat162float(hbh[j2 << 7]);
      a3 += __bfloat162float(hbh[j3 << 7]);
    }
    grid[(size_t)((i << 6) + c) * 128 + h] = __float2bfloat16((a0 + a1) + (a2 + a3));
  }
}

// ---------------- gemm: [2048 x 8192] bf16 @ W[n][k] bf16 -> f32 partials (split-K 16) ----------------
// BM=64, BN=128, BK=64; 4 waves, wave-tile 32x64; mfma_f32_16x16x32_bf16
// LDS rows are 128 B = 8 x 16B granules; XOR-swizzle granule with (row&7):
// stage source pre-swizzled (linear LDS dest, per global_load_lds constraint), read with same XOR.
__global__ __launch_bounds__(256) void sp_gemm(const __hip_bfloat16* __restrict__ Ag,
                                               const __hip_bfloat16* __restrict__ Wb,
                                               float* __restrict__ part) {
  __shared__ __align__(16) char Asm[8192];    // A tile [64][64] bf16
  __shared__ __align__(16) char Bsm[16384];   // B tile [128][64] bf16 (n-major)
  int t = threadIdx.x;
  int lane = t & 63;
  int w = t >> 6;
  int wm = w >> 1, wn = w & 1;
  int bx = blockIdx.x;
  int mt = bx & 31;     // 32 M-tiles of 64 rows
  int sp = bx >> 5;     // 16 K-splits of 512
  int i0 = mt * 64;
  long kbase = (long)sp * 512 * 2;  // byte offset of K-chunk within a row
  const char* Agc = (const char*)Ag;
  const char* Wbc = (const char*)Wb;
  f32x4 acc[2][4] = {};
  for (int st = 0; st < 8; ++st) {   // 8 K-steps of 64
    long kb = kbase + st * 128;
    #pragma unroll
    for (int q = 0; q < 2; ++q) {    // A: 8 KB
      int o = (q * 256 + t) * 16;
      int r = o >> 7;
      int sc = (o & 127) ^ ((r & 7) << 4);
      gl_lds16(Agc + (long)(i0 + r) * 16384 + kb + sc, Asm + o);
    }
    #pragma unroll
    for (int q = 0; q < 4; ++q) {    // B: 16 KB
      int o = (q * 256 + t) * 16;
      int r = o >> 7;
      int sc = (o & 127) ^ ((r & 7) << 4);
      gl_lds16(Wbc + (long)r * 16384 + kb + sc, Bsm + o);
    }
    __syncthreads();
    short8 af[2][2], bfr[4][2];
    #pragma unroll
    for (int fr = 0; fr < 2; ++fr)
      #pragma unroll
      for (int ks = 0; ks < 2; ++ks) {
        int r = wm * 32 + fr * 16 + (lane & 15);
        int g = ks * 4 + (lane >> 4);
        int byt = r * 128 + ((g ^ (r & 7)) << 4);
        af[fr][ks] = *reinterpret_cast<const short8*>(Asm + byt);
      }
    #pragma unroll
    for (int fc = 0; fc < 4; ++fc)
      #pragma unroll
      for (int ks = 0; ks < 2; ++ks) {
        int n = wn * 64 + fc * 16 + (lane & 15);
        int g = ks * 4 + (lane >> 4);
        int byt = n * 128 + ((g ^ (n & 7)) << 4);
        bfr[fc][ks] = *reinterpret_cast<const short8*>(Bsm + byt);
      }
    #pragma unroll
    for (int fr = 0; fr < 2; ++fr)
      #pragma unroll
      for (int fc = 0; fc < 4; ++fc)
        #pragma unroll
        for (int ks = 0; ks < 2; ++ks)
          acc[fr][fc] = __builtin_amdgcn_mfma_f32_16x16x32_bf16(af[fr][ks], bfr[fc][ks],
                                                                acc[fr][fc], 0, 0, 0);
    __syncthreads();
  }
  float* p = part + (long)sp * 262144;
  #pragma unroll
  for (int fr = 0; fr < 2; ++fr)
    #pragma unroll
    for (int fc = 0; fc < 4; ++fc)
      #pragma unroll
      for (int r4 = 0; r4 < 4; ++r4) {
        int ii = i0 + wm * 32 + fr * 16 + (lane >> 4) * 4 + r4;  // C/D: row=(lane>>4)*4+reg
        int nn = wn * 64 + fc * 16 + (lane & 15);                 // C/D: col=lane&15
        p[(long)ii * 128 + nn] = acc[fr][fc][r4];
      }
}

// ---------------- reduce: sum 16 partials + bias, apply valid_i mask ----------------
__global__ __launch_bounds__(256) void sp_reduce(const float* __restrict__ part,
                                                 const float* __restrict__ bias,
                                                 const float* __restrict__ pos,
                                                 const int* __restrict__ mask,
                                                 float* __restrict__ out) {
  int g = blockIdx.x * 256 + threadIdx.x;  // 0..262143
  int i = g >> 7, n = g & 127;
  float acc = bias[n];
  #pragma unroll
  for (int s = 0; s < 16; ++s) acc += part[(long)s * 262144 + g];
  float px = pos[2 * i], py = pos[2 * i + 1];
  bool vi = (mask[i] != 0) && (px == px) && (py == py);  // mask & ~isnan(pos).any
  out[g] = vi ? acc : 0.f;
}

extern "C" void kernel_launch(void* const* d_in, const int* in_sizes, int n_in,
                              void* d_out, int out_size, void* d_ws, size_t ws_size,
                              hipStream_t stream) {
  const float* hidden  = (const float*)d_in[0];
  const float* pos     = (const float*)d_in[1];
  const int*   mask    = (const int*)d_in[2];   // bool input -> int32 per harness contract
  const float* W       = (const float*)d_in[3];
  const float* bias    = (const float*)d_in[4];
  char* ws = (char*)d_ws;
  __hip_bfloat16* hb   = (__hip_bfloat16*)(ws + O_HB);
  __hip_bfloat16* wb   = (__hip_bfloat16*)(ws + O_WB);
  __hip_bfloat16* grid = (__hip_bfloat16*)(ws + O_GRID);
  float* part          = (float*)(ws + O_PART);
  uint16_t* listG      = (uint16_t*)(ws + O_LIST);
  int* offsG           = (int*)(ws + O_OFFS);
  float2* posm         = (float2*)(ws + O_POSM);
  float* out           = (float*)d_out;

  sp_prep<<<1289, 256, 0, stream>>>(hidden, W, pos, mask, hb, wb, posm);
  sp_bins<<<512, 256, 0, stream>>>(pos, posm, listG, offsG);
  sp_gath2<<<2048, 256, 0, stream>>>(listG, offsG, hb, grid);
  sp_gemm<<<512, 256, 0, stream>>>(grid, wb, part);
  sp_reduce<<<1024, 256, 0, stream>>>(part, bias, pos, mask, out);
}

// Round 11
// 81.171 us; speedup vs baseline: 1.1859x; 1.1859x over previous
//
#include <hip/hip_runtime.h>
#include <hip/hip_bf16.h>
#include <stdint.h>

// Problem constants: A=2048 agents, H=128, G=8 (64 cells), NB=32, CELL=8
// pooled = (grid[A,64,128] flattened) @ W.T + b ; out masked by valid_i.

typedef __attribute__((ext_vector_type(4))) float f32x4;
typedef __attribute__((ext_vector_type(8))) short short8;

// workspace layout (bytes)
#define O_HB   0u          // bf16 hidden [2049][128]  (row 2048 = zeros, dummy target)
#define O_WB   1048576u    // bf16 W      [128][8192]
#define O_GRID 3145728u    // bf16 grid   [2048][8192]
#define O_PART 36700160u   // f32 partials [16][2048][128] (written by gemm)
// Overlay of O_PART (consumed by sp_gath3 BEFORE sp_gemm writes part):
#define O_LIST 36700160u   // u16 lists [2048][2240] cell-sorted j (x4-padded, dummy=2048)
#define O_OFFS 46137344u   // int offs  [2048][65] padded exclusive offsets
#define O_POSM 46669824u   // float2 posm[2048] NaN-poisoned positions
// total ~51 MB

__device__ __forceinline__ void gl_lds16(const void* g, void* l) {
  __builtin_amdgcn_global_load_lds((const __attribute__((address_space(1))) void*)g,
                                   (__attribute__((address_space(3))) void*)l, 16, 0, 0);
}

__device__ __forceinline__ float bf_lo(uint32_t w) {
  union { uint32_t u; float f; } v{w << 16}; return v.f;
}
__device__ __forceinline__ float bf_hi(uint32_t w) {
  union { uint32_t u; float f; } v{w & 0xffff0000u}; return v.f;
}
__device__ __forceinline__ uint32_t pack_bf2(float x, float y) {
  __hip_bfloat16 bx = __float2bfloat16(x), by = __float2bfloat16(y);
  return ((uint32_t)(*(unsigned short*)&by) << 16) | (*(unsigned short*)&bx);
}

// ---------------- prep: f32 -> bf16 conversions + NaN-poisoned posm ----------------
__global__ __launch_bounds__(256) void sp_prep(const float* __restrict__ hidden,
                                               const float* __restrict__ W,
                                               const float* __restrict__ pos,
                                               const int* __restrict__ mask,
                                               __hip_bfloat16* __restrict__ hb,
                                               __hip_bfloat16* __restrict__ wb,
                                               float2* __restrict__ posm) {
  int idx = blockIdx.x * 256 + threadIdx.x;
  const int HID4 = (2049 * 128) / 4;   // 65568 groups of 4
  const int W4   = (128 * 8192) / 4;   // 262144 groups of 4
  if (idx < HID4) {
    int e = idx * 4;
    float4 v = make_float4(0.f, 0.f, 0.f, 0.f);
    if (e < 2048 * 128) v = *reinterpret_cast<const float4*>(hidden + e);
    ushort4 pk;
    pk.x = (ushort)(pack_bf2(v.x, v.x) & 0xffffu);
    pk.y = (ushort)(pack_bf2(v.y, v.y) & 0xffffu);
    pk.z = (ushort)(pack_bf2(v.z, v.z) & 0xffffu);
    pk.w = (ushort)(pack_bf2(v.w, v.w) & 0xffffu);
    *reinterpret_cast<ushort4*>(hb + e) = pk;
  } else if (idx < HID4 + W4) {
    int e = (idx - HID4) * 4;
    float4 v = *reinterpret_cast<const float4*>(W + e);
    ushort4 pk;
    pk.x = (ushort)(pack_bf2(v.x, v.x) & 0xffffu);
    pk.y = (ushort)(pack_bf2(v.y, v.y) & 0xffffu);
    pk.z = (ushort)(pack_bf2(v.z, v.z) & 0xffffu);
    pk.w = (ushort)(pack_bf2(v.w, v.w) & 0xffffu);
    *reinterpret_cast<ushort4*>(wb + e) = pk;
  } else {
    int j = idx - (HID4 + W4);
    if (j < 2048) {
      float2 p = reinterpret_cast<const float2*>(pos)[j];
      union { uint32_t u; float f; } qn{0x7fc00000u};  // quiet NaN
      float2 o;
      bool m = (mask[j] != 0);
      o.x = m ? p.x : qn.f;
      o.y = m ? p.y : qn.f;
      posm[j] = o;
    }
  }
}

// ---------------- bins: wave-per-agent counting sort -> GLOBAL u16 lists ----------------
// 512 blocks x 256 (4 waves), one agent per wave, wave-private. u16 j values,
// cells padded to x4 with dummy 2048 (zero row of hb), padded offsets offs[65].
__global__ __launch_bounds__(256) void sp_bins(const float* __restrict__ pos,
                                               const float2* __restrict__ posm,
                                               uint16_t* __restrict__ listG,
                                               int* __restrict__ offsG) {
  __shared__ int hist[4][64];
  __shared__ int curs[4][64];
  int t = threadIdx.x;
  int wv = t >> 6;
  int lane = t & 63;
  int i = blockIdx.x * 4 + wv;           // this wave's agent
  float pxi = pos[2 * i], pyi = pos[2 * i + 1];
  hist[wv][lane] = 0;
  // Phase A: bin all 2048 j's; pack 32 bins into 8 regs (byte each, static idx)
  uint32_t bp[8];
  #pragma unroll
  for (int r = 0; r < 8; ++r) bp[r] = 0;
  #pragma unroll
  for (int ch = 0; ch < 32; ++ch) {
    int j = ch * 64 + lane;
    float2 pj = posm[j];
    float rx = pj.x - pxi, ry = pj.y - pyi;
    // NaN rel (masked-out j or NaN pos) -> comparisons false -> invalid
    bool ok = (fabsf(rx) < 32.f) && (fabsf(ry) < 32.f) && (j != i);
    uint32_t b = 255;
    if (ok) {
      // rx,ry in (-32,32): (rx+32)*0.125 in [0,8) exactly; clip is a no-op
      int col = (int)floorf((rx + 32.f) * 0.125f);
      int row = (int)floorf((ry + 32.f) * 0.125f);
      b = (uint32_t)(row * 8 + col);
      atomicAdd(&hist[wv][b], 1);        // int LDS atomic (native)
    }
    bp[ch >> 2] |= b << ((ch & 3) * 8);
  }
  // Phase B: wave shfl prefix scan over x4-padded cell counts (lane = cell)
  int h = hist[wv][lane];
  int pc = (h + 3) & ~3;
  int x = pc;
  #pragma unroll
  for (int d = 1; d < 64; d <<= 1) {
    int y = __shfl_up(x, d);
    if (lane >= d) x += y;
  }
  int start = x - pc;
  curs[wv][lane] = start;
  offsG[i * 65 + lane] = start;
  if (lane == 63) offsG[i * 65 + 64] = x;   // total (padded)
  // Phase C: scatter u16 j (intra-wave int atomics only)
  uint16_t* lrow = listG + (size_t)i * 2240;
  #pragma unroll
  for (int ch = 0; ch < 32; ++ch) {
    uint32_t b = (bp[ch >> 2] >> ((ch & 3) * 8)) & 255u;
    if (b != 255u) {
      int slot = atomicAdd(&curs[wv][b], 1);
      lrow[slot] = (uint16_t)(ch * 64 + lane);
    }
  }
  // Phase Pad: lane = cell writes its own pad slots [start+h, start+pc) (disjoint)
  for (int p = h; p < pc; ++p) lrow[start + p] = 2048;
}

// ---------------- gath3: quad-wave row gather -- 4 rows per VMEM instruction -------
// 2048 blocks x 256 (one agent per block; wave wv takes cells c%4==wv).
// Lane = (quad = l>>4, li = l&15). Per 4-entry batch: ds_read_u16 list[k+quad]
// (16-lane broadcast groups), ONE global_load_dwordx4 at hb + (j<<8) + li*16
// (each quarter-wave covers a full 256B row), 16 unpack-adds into 8 f32 acc.
// Cell flush: shfl_xor(16)+shfl_xor(32), quad-0 packs bf16, 16 lanes store the
// 256B grid row. Empty cells store zeros (full grid coverage).
__global__ __launch_bounds__(256) void sp_gath3(const uint16_t* __restrict__ listG,
                                                const int* __restrict__ offsG,
                                                const __hip_bfloat16* __restrict__ hb,
                                                __hip_bfloat16* __restrict__ grid) {
  __shared__ __align__(8) uint16_t list[2304];
  __shared__ int offs[65];
  int t = threadIdx.x;
  int i = blockIdx.x;
  // copy offs + full list row into LDS (coalesced u32 reads)
  if (t < 65) offs[t] = offsG[i * 65 + t];
  {
    const uint32_t* lg = reinterpret_cast<const uint32_t*>(listG + (size_t)i * 2240);
    uint32_t* ll = reinterpret_cast<uint32_t*>(list);
    #pragma unroll
    for (int q = 0; q < 5; ++q) {
      int k = t + q * 256;
      if (k < 1120) ll[k] = lg[k];
    }
  }
  __syncthreads();
  int wv = t >> 6;
  int lane = t & 63;
  int quad = lane >> 4;       // which entry of the 4-batch this quarter-wave serves
  int li = lane & 15;         // 16B chunk within the 256B row
  uint32_t loff = (uint32_t)li * 16;
  const char* hbB = reinterpret_cast<const char*>(hb);
  char* gbase = reinterpret_cast<char*>(grid) + ((size_t)i << 14);
  for (int c = wv; c < 64; c += 4) {
    int s0 = offs[c], e0 = offs[c + 1];      // multiple of 4 entries
    float a0 = 0.f, a1 = 0.f, a2 = 0.f, a3 = 0.f;
    float a4 = 0.f, a5 = 0.f, a6 = 0.f, a7 = 0.f;
    for (int k = s0; k < e0; k += 4) {
      uint32_t j = (uint32_t)list[k + quad];   // 16-lane broadcast ds_read
      uint4 w = *reinterpret_cast<const uint4*>(hbB + (j << 8) + loff);
      a0 += bf_lo(w.x); a1 += bf_hi(w.x);
      a2 += bf_lo(w.y); a3 += bf_hi(w.y);
      a4 += bf_lo(w.z); a5 += bf_hi(w.z);
      a6 += bf_lo(w.w); a7 += bf_hi(w.w);
    }
    // reduce across the 4 quarter-waves (rows) -> quad 0 holds totals
    a0 += __shfl_xor(a0, 16); a1 += __shfl_xor(a1, 16);
    a2 += __shfl_xor(a2, 16); a3 += __shfl_xor(a3, 16);
    a4 += __shfl_xor(a4, 16); a5 += __shfl_xor(a5, 16);
    a6 += __shfl_xor(a6, 16); a7 += __shfl_xor(a7, 16);
    a0 += __shfl_xor(a0, 32); a1 += __shfl_xor(a1, 32);
    a2 += __shfl_xor(a2, 32); a3 += __shfl_xor(a3, 32);
    a4 += __shfl_xor(a4, 32); a5 += __shfl_xor(a5, 32);
    a6 += __shfl_xor(a6, 32); a7 += __shfl_xor(a7, 32);
    if (quad == 0) {   // 16 lanes x 16B = full 256B grid row for cell c
      uint4 o;
      o.x = pack_bf2(a0, a1);
      o.y = pack_bf2(a2, a3);
      o.z = pack_bf2(a4, a5);
      o.w = pack_bf2(a6, a7);
      *reinterpret_cast<uint4*>(gbase + (c << 8) + loff) = o;
    }
  }
}

// ---------------- gemm: [2048 x 8192] bf16 @ W[n][k] bf16 -> f32 partials (split-K 16) ----------------
// BM=64, BN=128, BK=64; 4 waves, wave-tile 32x64; mfma_f32_16x16x32_bf16
// LDS rows are 128 B = 8 x 16B granules; XOR-swizzle granule with (row&7):
// stage source pre-swizzled (linear LDS dest, per global_load_lds constraint), read with same XOR.
__global__ __launch_bounds__(256) void sp_gemm(const __hip_bfloat16* __restrict__ Ag,
                                               const __hip_bfloat16* __restrict__ Wb,
                                               float* __restrict__ part) {
  __shared__ __align__(16) char Asm[8192];    // A tile [64][64] bf16
  __shared__ __align__(16) char Bsm[16384];   // B tile [128][64] bf16 (n-major)
  int t = threadIdx.x;
  int lane = t & 63;
  int w = t >> 6;
  int wm = w >> 1, wn = w & 1;
  int bx = blockIdx.x;
  int mt = bx & 31;     // 32 M-tiles of 64 rows
  int sp = bx >> 5;     // 16 K-splits of 512
  int i0 = mt * 64;
  long kbase = (long)sp * 512 * 2;  // byte offset of K-chunk within a row
  const char* Agc = (const char*)Ag;
  const char* Wbc = (const char*)Wb;
  f32x4 acc[2][4] = {};
  for (int st = 0; st < 8; ++st) {   // 8 K-steps of 64
    long kb = kbase + st * 128;
    #pragma unroll
    for (int q = 0; q < 2; ++q) {    // A: 8 KB
      int o = (q * 256 + t) * 16;
      int r = o >> 7;
      int sc = (o & 127) ^ ((r & 7) << 4);
      gl_lds16(Agc + (long)(i0 + r) * 16384 + kb + sc, Asm + o);
    }
    #pragma unroll
    for (int q = 0; q < 4; ++q) {    // B: 16 KB
      int o = (q * 256 + t) * 16;
      int r = o >> 7;
      int sc = (o & 127) ^ ((r & 7) << 4);
      gl_lds16(Wbc + (long)r * 16384 + kb + sc, Bsm + o);
    }
    __syncthreads();
    short8 af[2][2], bfr[4][2];
    #pragma unroll
    for (int fr = 0; fr < 2; ++fr)
      #pragma unroll
      for (int ks = 0; ks < 2; ++ks) {
        int r = wm * 32 + fr * 16 + (lane & 15);
        int g = ks * 4 + (lane >> 4);
        int byt = r * 128 + ((g ^ (r & 7)) << 4);
        af[fr][ks] = *reinterpret_cast<const short8*>(Asm + byt);
      }
    #pragma unroll
    for (int fc = 0; fc < 4; ++fc)
      #pragma unroll
      for (int ks = 0; ks < 2; ++ks) {
        int n = wn * 64 + fc * 16 + (lane & 15);
        int g = ks * 4 + (lane >> 4);
        int byt = n * 128 + ((g ^ (n & 7)) << 4);
        bfr[fc][ks] = *reinterpret_cast<const short8*>(Bsm + byt);
      }
    #pragma unroll
    for (int fr = 0; fr < 2; ++fr)
      #pragma unroll
      for (int fc = 0; fc < 4; ++fc)
        #pragma unroll
        for (int ks = 0; ks < 2; ++ks)
          acc[fr][fc] = __builtin_amdgcn_mfma_f32_16x16x32_bf16(af[fr][ks], bfr[fc][ks],
                                                                acc[fr][fc], 0, 0, 0);
    __syncthreads();
  }
  float* p = part + (long)sp * 262144;
  #pragma unroll
  for (int fr = 0; fr < 2; ++fr)
    #pragma unroll
    for (int fc = 0; fc < 4; ++fc)
      #pragma unroll
      for (int r4 = 0; r4 < 4; ++r4) {
        int ii = i0 + wm * 32 + fr * 16 + (lane >> 4) * 4 + r4;  // C/D: row=(lane>>4)*4+reg
        int nn = wn * 64 + fc * 16 + (lane & 15);                 // C/D: col=lane&15
        p[(long)ii * 128 + nn] = acc[fr][fc][r4];
      }
}

// ---------------- reduce: sum 16 partials + bias, apply valid_i mask ----------------
__global__ __launch_bounds__(256) void sp_reduce(const float* __restrict__ part,
                                                 const float* __restrict__ bias,
                                                 const float* __restrict__ pos,
                                                 const int* __restrict__ mask,
                                                 float* __restrict__ out) {
  int g = blockIdx.x * 256 + threadIdx.x;  // 0..262143
  int i = g >> 7, n = g & 127;
  float acc = bias[n];
  #pragma unroll
  for (int s = 0; s < 16; ++s) acc += part[(long)s * 262144 + g];
  float px = pos[2 * i], py = pos[2 * i + 1];
  bool vi = (mask[i] != 0) && (px == px) && (py == py);  // mask & ~isnan(pos).any
  out[g] = vi ? acc : 0.f;
}

extern "C" void kernel_launch(void* const* d_in, const int* in_sizes, int n_in,
                              void* d_out, int out_size, void* d_ws, size_t ws_size,
                              hipStream_t stream) {
  const float* hidden  = (const float*)d_in[0];
  const float* pos     = (const float*)d_in[1];
  const int*   mask    = (const int*)d_in[2];   // bool input -> int32 per harness contract
  const float* W       = (const float*)d_in[3];
  const float* bias    = (const float*)d_in[4];
  char* ws = (char*)d_ws;
  __hip_bfloat16* hb   = (__hip_bfloat16*)(ws + O_HB);
  __hip_bfloat16* wb   = (__hip_bfloat16*)(ws + O_WB);
  __hip_bfloat16* grid = (__hip_bfloat16*)(ws + O_GRID);
  float* part          = (float*)(ws + O_PART);
  uint16_t* listG      = (uint16_t*)(ws + O_LIST);
  int* offsG           = (int*)(ws + O_OFFS);
  float2* posm         = (float2*)(ws + O_POSM);
  float* out           = (float*)d_out;

  sp_prep<<<1289, 256, 0, stream>>>(hidden, W, pos, mask, hb, wb, posm);
  sp_bins<<<512, 256, 0, stream>>>(pos, posm, listG, offsG);
  sp_gath3<<<2048, 256, 0, stream>>>(listG, offsG, hb, grid);
  sp_gemm<<<512, 256, 0, stream>>>(grid, wb, part);
  sp_reduce<<<1024, 256, 0, stream>>>(part, bias, pos, mask, out);
}